// Round 8
// baseline (380.995 us; speedup 1.0000x reference)
//
#include <hip/hip_runtime.h>
#include <stdint.h>

// Problem constants (n=6, d=1024, T=4096)
#define T_STEPS 4096
#define DDIM    1024
#define CH      64    // chunks (both pipelines)
#define CL      64    // steps per chunk
#define MEAN_ELEMS ((size_t)T_STEPS * 6 * DDIM)   // 25,165,824

#define PF1 8   // km1 nmean prefetch depth (8*6=48 outstanding <= 63 vmcnt cap)
#define PF3 4   // km3 depth (loads+stores: 3*12+6=42 <= 63)

__device__ __forceinline__ float bf2f(uint16_t h){
    return __uint_as_float(((uint32_t)h) << 16);
}
__device__ __forceinline__ uint16_t f2bf(float f){   // round-to-nearest-even
    uint32_t u = __float_as_uint(f);
    uint32_t r = 0x7FFFu + ((u >> 16) & 1u);
    return (uint16_t)((u + r) >> 16);
}
// dtype-flag-aware scalar load (flag: 1 = inputs are float32, 0 = bf16)
__device__ __forceinline__ float ld(const void* p, size_t idx, bool f32){
    return f32 ? ((const float*)p)[idx] : bf2f(((const uint16_t*)p)[idx]);
}
template<bool F32>
__device__ __forceinline__ float ldn(const void* p, size_t idx){
    return F32 ? ((const float*)p)[idx] : bf2f(((const uint16_t*)p)[idx]);
}

// Per-wave dtype detect (lanes 0..63 of wave 0 call this; same data every
// block -> deterministic). Returns 1 if inputs are f32, 0 if bf16.
__device__ __forceinline__ uint32_t detect_wave(const void* imean){
    const uint32_t* w = (const uint32_t*)imean;
    int good = 0;
    for (int i = (int)(threadIdx.x & 63); i < 3072; i += 64){
        float v = bf2f((uint16_t)(w[i] & 0xFFFFu));
        float a = fabsf(v);
        if (a > 1e-6f && a < 1e4f) good++;
    }
    #pragma unroll
    for (int ofs = 32; ofs >= 1; ofs >>= 1) good += __shfl_xor(good, ofs, 64);
    return (good < 2000) ? 1u : 0u;
}

// ---------------------------------------------------------------------------
// K1: per-chunk composition M' = A M A^T + N (Gram recursion), 64-step chunks.
// Wave-synchronous shuffle recursion: lane e=(i,j) keeps P[i][j],Q[i][j] in
// registers; cross-lane operands via __shfl (single wave => lockstep, ZERO
// barriers in the step loop). Was: 2 barriers + LDS round-trips = ~2250
// cycles/step, 60 us. FMA order over m identical -> bitwise-same results.
// ---------------------------------------------------------------------------
__global__ void __launch_bounds__(64)
k1_chunk_compose(const void* __restrict__ imean,
                 const void* __restrict__ trans,
                 const void* __restrict__ ncov,
                 double* __restrict__ Pd, double* __restrict__ Qd,
                 float* __restrict__ Pf){
    __shared__ float As[CL*36], Ns[CL*36];
    __shared__ uint32_t s_flag;
    const int c = blockIdx.x;
    const int e = threadIdx.x;
    const int ec = (e < 36) ? e : 0;       // lanes 36-63 mirror lane 0 (discarded)
    const int i = ec / 6, j = ec % 6;
    const int i6 = i*6, j6 = j*6;
    {
        uint32_t fl = detect_wave(imean);
        if (e == 0) s_flag = fl;
    }
    __syncthreads();
    const bool f32 = s_flag != 0;
    for (int idx = e; idx < CL*36; idx += 64){
        const size_t g = (size_t)c*CL*36 + idx;
        As[idx] = ld(trans, g, f32);
        Ns[idx] = ld(ncov,  g, f32);
    }
    __syncthreads();
    double P = (i == j) ? 1.0 : 0.0, Q = 0.0;
    for (int s = 0; s < CL; ++s){
        const float* A  = As + s*36;
        const float* Nn = Ns + s*36;
        double newP = 0.0, Tij = 0.0;
        #pragma unroll
        for (int m = 0; m < 6; ++m){
            double am = (double)A[i6+m];
            newP += am * __shfl(P, m*6+j, 64);   // P[m][j]
            Tij  += am * __shfl(Q, m*6+j, 64);   // Q[m][j]
        }
        double qn = 0.0;
        #pragma unroll
        for (int m = 0; m < 6; ++m){
            qn += __shfl(Tij, i6+m, 64) * (double)A[j6+m];     // T[i][m]*A[j][m]
            qn += (double)Nn[i6+m] * (double)Nn[j6+m];         // + n n^T
        }
        P = newP; Q = qn;
    }
    if (e < 36){
        Pd[c*36+e] = P;
        Qd[c*36+e] = Q;
        Pf[c*36+e] = (float)P;
    }
}

// ---------------------------------------------------------------------------
// K2: boundary scan; Ps/Qs staged to LDS, M in lane registers, shuffle
// recursion, zero barriers in the 63-iteration loop. Single wave.
// ---------------------------------------------------------------------------
__global__ void __launch_bounds__(64)
k2_boundary_scan(const void* __restrict__ imean,
                 const void* __restrict__ icov,
                 const double* __restrict__ Pd,
                 const double* __restrict__ Qd,
                 double* __restrict__ Mb){
    __shared__ double Ps[CH*36], Qs[CH*36];
    __shared__ double l_ds[36];
    __shared__ uint32_t s_flag;
    const int e = threadIdx.x;
    const int ec = (e < 36) ? e : 0;
    const int i = ec / 6, j = ec % 6;
    const int i6 = i*6, j6 = j*6;
    {
        uint32_t fl = detect_wave(imean);
        if (e == 0) s_flag = fl;
    }
    __syncthreads();
    const bool f32 = s_flag != 0;
    for (int idx = e; idx < CH*36; idx += 64){
        Ps[idx] = Pd[idx];
        Qs[idx] = Qd[idx];
    }
    if (e < 36) l_ds[e] = (double)ld(icov, e, f32);
    __syncthreads();
    double M = 0.0;
    #pragma unroll
    for (int mm = 0; mm < 6; ++mm) M += l_ds[i6+mm] * l_ds[j6+mm];
    if (e < 36) Mb[e] = M;
    for (int cc = 0; cc < CH - 1; ++cc){
        const double* Pc = Ps + cc*36;
        double t = 0.0;
        #pragma unroll
        for (int m = 0; m < 6; ++m) t += Pc[i6+m] * __shfl(M, m*6+j, 64);
        double mn = 0.0;
        #pragma unroll
        for (int m = 0; m < 6; ++m) mn += __shfl(t, i6+m, 64) * Pc[j6+m];
        mn += Qs[cc*36 + ec];
        M = mn;
        if (e < 36) Mb[(cc+1)*36 + e] = mn;
    }
}

// ---------------------------------------------------------------------------
// K34: fused expand+QR. Expand is the shuffle recursion (zero barriers);
// each step's M is stored to Mst (stride 37) for the per-thread QR. One
// barrier between expand and QR. Math bitwise-identical to round-7 k34.
// ---------------------------------------------------------------------------
__global__ void __launch_bounds__(64)
k34_expand_qr(const void* __restrict__ imean,
              const void* __restrict__ icov,
              const void* __restrict__ trans,
              const void* __restrict__ ncov,
              const double* __restrict__ Mb,
              void* __restrict__ d_out,
              uint32_t* __restrict__ masks,
              uint32_t* __restrict__ chunkTot){
    __shared__ float As[CL*36], Ns[CL*36];
    __shared__ double Mst[CL*37];            // stride 37: avoid row aliasing
    __shared__ uint32_t s_flag;
    const int c = blockIdx.x;
    const int e = threadIdx.x;
    const int ec = (e < 36) ? e : 0;
    const int i = ec / 6, j = ec % 6;
    const int i6 = i*6, j6 = j*6;
    {
        uint32_t fl = detect_wave(imean);
        if (e == 0) s_flag = fl;
    }
    __syncthreads();
    const bool f32 = s_flag != 0;

    for (int idx = e; idx < CL*36; idx += 64){
        const size_t g = (size_t)c*CL*36 + idx;
        As[idx] = ld(trans, g, f32);
        Ns[idx] = ld(ncov,  g, f32);
    }
    __syncthreads();

    // expand: register M, shuffle recursion; store each step's M to Mst
    double M = Mb[c*36 + ec];
    for (int s = 0; ; ++s){
        if (e < 36) Mst[s*37 + e] = M;       // M entering step s
        if (s == CL - 1) break;              // uniform
        const float* A  = As + s*36;
        const float* Nn = Ns + s*36;
        double t = 0.0;
        #pragma unroll
        for (int m = 0; m < 6; ++m) t += (double)A[i6+m] * __shfl(M, m*6+j, 64);
        double mn = 0.0;
        #pragma unroll
        for (int m = 0; m < 6; ++m){
            mn += __shfl(t, i6+m, 64) * (double)A[j6+m];
            mn += (double)Nn[i6+m] * (double)Nn[j6+m];
        }
        M = mn;
    }
    __syncthreads();

    // per-thread QR of step k = c*64 + e (identical math to round-7 k34)
    const int k = c*CL + e;
    double X[12][6];
    if (k == 0){
        double l0[6][6], A0[6][6];
        #pragma unroll
        for (int a = 0; a < 36; ++a){
            l0[a/6][a%6] = (double)ld(icov, a, f32);
            A0[a/6][a%6] = (double)As[a];
        }
        #pragma unroll
        for (int i2 = 0; i2 < 6; ++i2)
            #pragma unroll
            for (int j2 = 0; j2 < 6; ++j2){
                double s = 0.0;
                #pragma unroll
                for (int m = 0; m < 6; ++m) s += A0[i2][m] * l0[m][j2];
                X[j2][i2] = s;               // top block = (A l)^T
            }
    } else {
        double Mx[6][6];
        #pragma unroll
        for (int a = 0; a < 36; ++a) Mx[a/6][a%6] = Mst[e*37 + a];
        // Cholesky in place
        #pragma unroll
        for (int j2 = 0; j2 < 6; ++j2){
            double d = Mx[j2][j2];
            #pragma unroll
            for (int m = 0; m < 6; ++m) if (m < j2) d -= Mx[j2][m]*Mx[j2][m];
            d = (d > 1e-300) ? d : 1e-300;
            double cjj = sqrt(d);
            Mx[j2][j2] = cjj;
            double inv = 1.0 / cjj;
            #pragma unroll
            for (int i2 = 0; i2 < 6; ++i2){
                if (i2 > j2){
                    double s = Mx[i2][j2];
                    #pragma unroll
                    for (int m = 0; m < 6; ++m) if (m < j2) s -= Mx[i2][m]*Mx[j2][m];
                    Mx[i2][j2] = s * inv;
                }
            }
        }
        #pragma unroll
        for (int i2 = 0; i2 < 6; ++i2){
            double Arow[6];
            #pragma unroll
            for (int m = 0; m < 6; ++m) Arow[m] = (double)As[e*36 + i2*6 + m];
            #pragma unroll
            for (int j2 = 0; j2 < 6; ++j2){
                double s = 0.0;
                #pragma unroll
                for (int m = 0; m < 6; ++m) if (m >= j2) s += Arow[m] * Mx[m][j2];
                X[j2][i2] = s;               // top block = (A C)^T
            }
        }
    }
    // bottom block = n^T
    #pragma unroll
    for (int r = 0; r < 6; ++r)
        #pragma unroll
        for (int c2 = 0; c2 < 6; ++c2)
            X[6+r][c2] = (double)Ns[e*36 + c2*6 + r];

    // In-place Householder QR, LAPACK sign convention
    #pragma unroll
    for (int kk = 0; kk < 6; ++kk){
        double alpha = X[kk][kk];
        double xn2 = 0.0;
        #pragma unroll
        for (int i2 = 0; i2 < 12; ++i2) if (i2 > kk) xn2 += X[i2][kk]*X[i2][kk];
        if (xn2 != 0.0){
            double nrm  = sqrt(alpha*alpha + xn2);
            double beta = (alpha >= 0.0) ? -nrm : nrm;
            double tau  = (beta - alpha) / beta;
            double sc   = 1.0 / (alpha - beta);
            #pragma unroll
            for (int i2 = 0; i2 < 12; ++i2) if (i2 > kk) X[i2][kk] *= sc;
            X[kk][kk] = beta;
            #pragma unroll
            for (int j2 = 0; j2 < 6; ++j2){
                if (j2 > kk){
                    double w = X[kk][j2];
                    #pragma unroll
                    for (int i2 = 0; i2 < 12; ++i2) if (i2 > kk) w += X[i2][kk]*X[i2][j2];
                    double wt = tau * w;
                    X[kk][j2] -= wt;
                    #pragma unroll
                    for (int i2 = 0; i2 < 12; ++i2) if (i2 > kk) X[i2][j2] -= X[i2][kk]*wt;
                }
            }
        }
    }

    uint32_t mask = 0;
    #pragma unroll
    for (int j2 = 0; j2 < 6; ++j2) if (X[j2][j2] < 0.0) mask |= (1u << j2);
    masks[k] = mask;

    // per-chunk XOR total for k56's cross-chunk prefix
    uint32_t incl = mask;
    #pragma unroll
    for (int ofs = 1; ofs < 64; ofs <<= 1){
        uint32_t up = (uint32_t)__shfl_up((int)incl, ofs, 64);
        if (e >= ofs) incl ^= up;
    }
    if (e == 63) chunkTot[c] = incl;

    if (f32){
        float* o = (float*)d_out + MEAN_ELEMS + (size_t)k*36;
        #pragma unroll
        for (int i2 = 0; i2 < 6; ++i2)
            #pragma unroll
            for (int j2 = 0; j2 < 6; ++j2)
                o[i2*6 + j2] = (j2 <= i2) ? (float)X[j2][i2] : 0.0f;
    } else {
        uint16_t* o = (uint16_t*)d_out + MEAN_ELEMS + (size_t)k*36;
        #pragma unroll
        for (int i2 = 0; i2 < 6; ++i2)
            #pragma unroll
            for (int j2 = 0; j2 < 6; ++j2)
                o[i2*6 + j2] = f2bf((j2 <= i2) ? (float)X[j2][i2] : 0.0f);
    }
}

// ---------------------------------------------------------------------------
// K56: fused k5+k6. amask[k] = XOR(chunkTot[<c]) ^ in-wave exclusive prefix
// of this chunk's masks, then apply column sign flips (sign-bit XOR).
// ---------------------------------------------------------------------------
__global__ void __launch_bounds__(64)
k56_sign_apply(const void* __restrict__ imean,
               void* __restrict__ d_out,
               const uint32_t* __restrict__ masks,
               const uint32_t* __restrict__ chunkTot){
    __shared__ uint32_t s_flag;
    const int c = blockIdx.x;
    const int e = threadIdx.x;
    {
        uint32_t fl = detect_wave(imean);
        if (e == 0) s_flag = fl;
    }
    __syncthreads();
    const bool f32 = s_flag != 0;
    const int k = c*CL + e;
    const uint32_t m = masks[k];
    uint32_t incl = m;
    #pragma unroll
    for (int ofs = 1; ofs < 64; ofs <<= 1){
        uint32_t up = (uint32_t)__shfl_up((int)incl, ofs, 64);
        if (e >= ofs) incl ^= up;
    }
    const uint32_t excl = incl ^ m;
    uint32_t v = (e < c) ? chunkTot[e] : 0u;   // c<=63 -> lanes 0..62 suffice
    #pragma unroll
    for (int ofs = 32; ofs >= 1; ofs >>= 1) v ^= (uint32_t)__shfl_xor((int)v, ofs, 64);
    const uint32_t am = v ^ excl;              // == old amask[k]
    if (am == 0u) return;
    if (f32){
        uint32_t* o = (uint32_t*)d_out + MEAN_ELEMS + (size_t)k*36;
        #pragma unroll
        for (int t = 0; t < 36; ++t)
            if ((am >> (t % 6)) & 1u) o[t] ^= 0x80000000u;
    } else {
        uint16_t* o = (uint16_t*)d_out + MEAN_ELEMS + (size_t)k*36;
        #pragma unroll
        for (int t = 0; t < 36; ++t)
            if ((am >> (t % 6)) & 1u) o[t] ^= 0x8000u;
    }
}

// ---------------------------------------------------------------------------
// Means pipeline (identical FMA order to passing round-7).
// ---------------------------------------------------------------------------
template<bool F32>
__device__ __forceinline__ void km1_body(const void* __restrict__ nmean,
                                         const float* __restrict__ As,
                                         float* __restrict__ r_ws, int c, int col){
    float r[6];
    #pragma unroll
    for (int i = 0; i < 6; ++i) r[i] = 0.f;
    float pb[PF1][6];
    const size_t base = (size_t)c*CL*6144 + col;
    #pragma unroll
    for (int p = 0; p < PF1; ++p)
        #pragma unroll
        for (int i = 0; i < 6; ++i)
            pb[p][i] = ldn<F32>(nmean, base + (size_t)p*6144 + i*DDIM);
    for (int s0 = 0; s0 < CL; s0 += PF1){
        const bool pf = (s0 + PF1 < CL);     // uniform
        #pragma unroll
        for (int p = 0; p < PF1; ++p){
            const int s = s0 + p;
            float n[6];
            #pragma unroll
            for (int i = 0; i < 6; ++i) n[i] = pb[p][i];
            if (pf){
                #pragma unroll
                for (int i = 0; i < 6; ++i)
                    pb[p][i] = ldn<F32>(nmean, base + (size_t)(s + PF1)*6144 + i*DDIM);
            }
            const float* A = As + s*36;      // LDS (lgkmcnt, not vmcnt)
            float acc[6];
            #pragma unroll
            for (int i = 0; i < 6; ++i){
                float t = n[i];
                #pragma unroll
                for (int m = 0; m < 6; ++m) t += A[i*6+m]*r[m];
                acc[i] = t;
            }
            #pragma unroll
            for (int i = 0; i < 6; ++i) r[i] = acc[i];
        }
    }
    float* out = r_ws + (size_t)c*6144;
    #pragma unroll
    for (int i = 0; i < 6; ++i) out[i*DDIM + col] = r[i];
}

__global__ void __launch_bounds__(256)
km1_chunk_r(const void* __restrict__ imean, const void* __restrict__ trans,
            const void* __restrict__ nmean,
            float* __restrict__ r_ws){
    __shared__ float As[CL*36];
    __shared__ uint32_t s_flag;
    if (threadIdx.x < 64){
        uint32_t fl = detect_wave(imean);
        if (threadIdx.x == 0) s_flag = fl;
    }
    __syncthreads();
    const bool f32 = s_flag != 0;
    const int c = blockIdx.x >> 2;
    for (int idx = threadIdx.x; idx < CL*36; idx += 256)
        As[idx] = ld(trans, (size_t)c*CL*36 + idx, f32);
    __syncthreads();
    const int col = (blockIdx.x & 3)*256 + threadIdx.x;
    if (f32) km1_body<true >(nmean, As, r_ws, c, col);
    else     km1_body<false>(nmean, As, r_ws, c, col);
}

// KM2: Pf fully staged to LDS; r prefetched 4 chunks deep (counted vmcnt).
__global__ void __launch_bounds__(256)
km2_scan(const void* __restrict__ imean,
         const float* __restrict__ Pf,
         const float* __restrict__ r_ws,
         float* __restrict__ mb_ws){
    __shared__ float Ps[CH*36];
    __shared__ uint32_t s_flag;
    if (threadIdx.x < 64){
        uint32_t fl = detect_wave(imean);
        if (threadIdx.x == 0) s_flag = fl;
    }
    __syncthreads();
    const bool f32 = s_flag != 0;
    for (int idx = threadIdx.x; idx < CH*36; idx += 256) Ps[idx] = Pf[idx];
    __syncthreads();
    const int col = blockIdx.x*256 + threadIdx.x;   // 4 blocks x 256 = 1024 cols
    float m[6];
    #pragma unroll
    for (int i = 0; i < 6; ++i) m[i] = ld(imean, (size_t)i*DDIM + col, f32);
    float rb[4][6];
    #pragma unroll
    for (int p = 0; p < 4; ++p)
        #pragma unroll
        for (int i = 0; i < 6; ++i) rb[p][i] = r_ws[(size_t)p*6144 + i*DDIM + col];
    for (int c0 = 0; c0 < CH; c0 += 4){
        const bool pf = (c0 + 4 < CH);       // uniform
        #pragma unroll
        for (int p = 0; p < 4; ++p){
            const int c = c0 + p;
            float rc[6];
            #pragma unroll
            for (int i = 0; i < 6; ++i) rc[i] = rb[p][i];
            if (pf){
                #pragma unroll
                for (int i = 0; i < 6; ++i)
                    rb[p][i] = r_ws[(size_t)(c+4)*6144 + i*DDIM + col];
            }
            float* mb = mb_ws + (size_t)c*6144;
            #pragma unroll
            for (int i = 0; i < 6; ++i) mb[i*DDIM + col] = m[i];
            float nm[6];
            #pragma unroll
            for (int i = 0; i < 6; ++i){
                float s0 = rc[i];
                #pragma unroll
                for (int mm = 0; mm < 6; ++mm) s0 += Ps[c*36 + i*6+mm]*m[mm];
                nm[i] = s0;
            }
            #pragma unroll
            for (int i = 0; i < 6; ++i) m[i] = nm[i];
        }
    }
}

// KM3: replay within chunk from exact boundary, write means (dtype-aware).
template<bool F32>
__device__ __forceinline__ void km3_body(const void* __restrict__ nmean,
                                         const float* __restrict__ As,
                                         const float* __restrict__ mb_ws,
                                         void* __restrict__ means_out,
                                         int c, int col){
    float m[6];
    const float* mb = mb_ws + (size_t)c*6144;
    #pragma unroll
    for (int i = 0; i < 6; ++i) m[i] = mb[i*DDIM + col];
    float pb[PF3][6];
    const size_t base = (size_t)c*CL*6144 + col;
    #pragma unroll
    for (int p = 0; p < PF3; ++p)
        #pragma unroll
        for (int i = 0; i < 6; ++i)
            pb[p][i] = ldn<F32>(nmean, base + (size_t)p*6144 + i*DDIM);
    for (int s0 = 0; s0 < CL; s0 += PF3){
        const bool pf = (s0 + PF3 < CL);     // uniform
        #pragma unroll
        for (int p = 0; p < PF3; ++p){
            const int s = s0 + p;
            float n[6];
            #pragma unroll
            for (int i = 0; i < 6; ++i) n[i] = pb[p][i];
            if (pf){
                #pragma unroll
                for (int i = 0; i < 6; ++i)
                    pb[p][i] = ldn<F32>(nmean, base + (size_t)(s + PF3)*6144 + i*DDIM);
            }
            const int k = c*CL + s;
            const float* A = As + s*36;      // LDS
            float acc[6];
            #pragma unroll
            for (int i = 0; i < 6; ++i){
                float t = n[i];
                #pragma unroll
                for (int mm = 0; mm < 6; ++mm) t += A[i*6+mm]*m[mm];
                acc[i] = t;
            }
            #pragma unroll
            for (int i = 0; i < 6; ++i){
                m[i] = acc[i];
                if (F32){
                    ((float*)means_out)[(size_t)k*6144 + i*DDIM + col] = m[i];
                } else {
                    ((uint16_t*)means_out)[(size_t)k*6144 + i*DDIM + col] = f2bf(m[i]);
                }
            }
        }
    }
}

__global__ void __launch_bounds__(256)
km3_final(const void* __restrict__ imean, const void* __restrict__ trans,
          const void* __restrict__ nmean,
          const float* __restrict__ mb_ws, void* __restrict__ means_out){
    __shared__ float As[CL*36];
    __shared__ uint32_t s_flag;
    if (threadIdx.x < 64){
        uint32_t fl = detect_wave(imean);
        if (threadIdx.x == 0) s_flag = fl;
    }
    __syncthreads();
    const bool f32 = s_flag != 0;
    const int c = blockIdx.x >> 2;
    for (int idx = threadIdx.x; idx < CL*36; idx += 256)
        As[idx] = ld(trans, (size_t)c*CL*36 + idx, f32);
    __syncthreads();
    const int col = (blockIdx.x & 3)*256 + threadIdx.x;
    if (f32) km3_body<true >(nmean, As, mb_ws, means_out, c, col);
    else     km3_body<false>(nmean, As, mb_ws, means_out, c, col);
}

// ---------------------------------------------------------------------------
extern "C" void kernel_launch(void* const* d_in, const int* in_sizes, int n_in,
                              void* d_out, int out_size, void* d_ws, size_t ws_size,
                              hipStream_t stream){
    (void)in_sizes; (void)n_in; (void)out_size; (void)ws_size;
    const void* imean = d_in[0];  // [6,1024]
    const void* icov  = d_in[1];  // [6,6]
    const void* trans = d_in[2];  // [T,6,6]
    const void* nmean = d_in[3];  // [T,6,1024]
    const void* ncov  = d_in[4];  // [T,6,6]

    // workspace layout (8-byte types first; ~3.2 MB total)
    char* w = (char*)d_ws;
    double* Pd   = (double*)w; w += (size_t)CH*36*8;
    double* Qd   = (double*)w; w += (size_t)CH*36*8;
    double* Mb   = (double*)w; w += (size_t)CH*36*8;
    float*  Pf   = (float*)w;  w += (size_t)CH*36*4;
    uint32_t* masks    = (uint32_t*)w; w += (size_t)T_STEPS*4;
    uint32_t* chunkTot = (uint32_t*)w; w += (size_t)CH*4;
    float* r_ws  = (float*)w;  w += (size_t)CH*6*DDIM*4;
    float* mb_ws = (float*)w;  w += (size_t)CH*6*DDIM*4;

    k1_chunk_compose<<<CH, 64, 0, stream>>>(imean, trans, ncov, Pd, Qd, Pf);
    k2_boundary_scan<<<1, 64, 0, stream>>>(imean, icov, Pd, Qd, Mb);
    km1_chunk_r<<<4*CH, 256, 0, stream>>>(imean, trans, nmean, r_ws);
    km2_scan<<<4, 256, 0, stream>>>(imean, Pf, r_ws, mb_ws);
    km3_final<<<4*CH, 256, 0, stream>>>(imean, trans, nmean, mb_ws, d_out);
    k34_expand_qr<<<CH, 64, 0, stream>>>(imean, icov, trans, ncov, Mb, d_out, masks, chunkTot);
    k56_sign_apply<<<CH, 64, 0, stream>>>(imean, d_out, masks, chunkTot);
}

// Round 9
// 366.315 us; speedup vs baseline: 1.0401x; 1.0401x over previous
//
#include <hip/hip_runtime.h>
#include <stdint.h>

// Problem constants (n=6, d=1024, T=4096)
#define T_STEPS 4096
#define DDIM    1024
#define CH      64    // chunks (both pipelines)
#define CL      64    // steps per chunk
#define MEAN_ELEMS ((size_t)T_STEPS * 6 * DDIM)   // 25,165,824

#define PF1 8   // km1 nmean prefetch depth (8*6=48 outstanding <= 63 vmcnt cap)
#define PF3 4   // km3 depth (loads+stores: 3*12+6=42 <= 63)

__device__ __forceinline__ float bf2f(uint16_t h){
    return __uint_as_float(((uint32_t)h) << 16);
}
__device__ __forceinline__ uint16_t f2bf(float f){   // round-to-nearest-even
    uint32_t u = __float_as_uint(f);
    uint32_t r = 0x7FFFu + ((u >> 16) & 1u);
    return (uint16_t)((u + r) >> 16);
}
// dtype-flag-aware scalar load (flag: 1 = inputs are float32, 0 = bf16)
__device__ __forceinline__ float ld(const void* p, size_t idx, bool f32){
    return f32 ? ((const float*)p)[idx] : bf2f(((const uint16_t*)p)[idx]);
}
template<bool F32>
__device__ __forceinline__ float ldn(const void* p, size_t idx){
    return F32 ? ((const float*)p)[idx] : bf2f(((const uint16_t*)p)[idx]);
}

// Per-wave dtype detect (one wave; same data every block -> deterministic).
__device__ __forceinline__ uint32_t detect_wave(const void* imean){
    const uint32_t* w = (const uint32_t*)imean;
    int good = 0;
    for (int i = (int)(threadIdx.x & 63); i < 3072; i += 64){
        float v = bf2f((uint16_t)(w[i] & 0xFFFFu));
        float a = fabsf(v);
        if (a > 1e-6f && a < 1e4f) good++;
    }
    #pragma unroll
    for (int ofs = 32; ofs >= 1; ofs >>= 1) good += __shfl_xor(good, ofs, 64);
    return (good < 2000) ? 1u : 0u;
}

// ---------------------------------------------------------------------------
// Means bodies (verbatim from passing round-8 kernel).
// ---------------------------------------------------------------------------
template<bool F32>
__device__ __forceinline__ void km1_body(const void* __restrict__ nmean,
                                         const float* __restrict__ As,
                                         float* __restrict__ r_ws, int c, int col){
    float r[6];
    #pragma unroll
    for (int i = 0; i < 6; ++i) r[i] = 0.f;
    float pb[PF1][6];
    const size_t base = (size_t)c*CL*6144 + col;
    #pragma unroll
    for (int p = 0; p < PF1; ++p)
        #pragma unroll
        for (int i = 0; i < 6; ++i)
            pb[p][i] = ldn<F32>(nmean, base + (size_t)p*6144 + i*DDIM);
    for (int s0 = 0; s0 < CL; s0 += PF1){
        const bool pf = (s0 + PF1 < CL);     // uniform
        #pragma unroll
        for (int p = 0; p < PF1; ++p){
            const int s = s0 + p;
            float n[6];
            #pragma unroll
            for (int i = 0; i < 6; ++i) n[i] = pb[p][i];
            if (pf){
                #pragma unroll
                for (int i = 0; i < 6; ++i)
                    pb[p][i] = ldn<F32>(nmean, base + (size_t)(s + PF1)*6144 + i*DDIM);
            }
            const float* A = As + s*36;      // LDS (lgkmcnt, not vmcnt)
            float acc[6];
            #pragma unroll
            for (int i = 0; i < 6; ++i){
                float t = n[i];
                #pragma unroll
                for (int m = 0; m < 6; ++m) t += A[i*6+m]*r[m];
                acc[i] = t;
            }
            #pragma unroll
            for (int i = 0; i < 6; ++i) r[i] = acc[i];
        }
    }
    float* out = r_ws + (size_t)c*6144;
    #pragma unroll
    for (int i = 0; i < 6; ++i) out[i*DDIM + col] = r[i];
}

template<bool F32>
__device__ __forceinline__ void km3_body(const void* __restrict__ nmean,
                                         const float* __restrict__ As,
                                         const float* __restrict__ mb_ws,
                                         void* __restrict__ means_out,
                                         int c, int col){
    float m[6];
    const float* mb = mb_ws + (size_t)c*6144;
    #pragma unroll
    for (int i = 0; i < 6; ++i) m[i] = mb[i*DDIM + col];
    float pb[PF3][6];
    const size_t base = (size_t)c*CL*6144 + col;
    #pragma unroll
    for (int p = 0; p < PF3; ++p)
        #pragma unroll
        for (int i = 0; i < 6; ++i)
            pb[p][i] = ldn<F32>(nmean, base + (size_t)p*6144 + i*DDIM);
    for (int s0 = 0; s0 < CL; s0 += PF3){
        const bool pf = (s0 + PF3 < CL);     // uniform
        #pragma unroll
        for (int p = 0; p < PF3; ++p){
            const int s = s0 + p;
            float n[6];
            #pragma unroll
            for (int i = 0; i < 6; ++i) n[i] = pb[p][i];
            if (pf){
                #pragma unroll
                for (int i = 0; i < 6; ++i)
                    pb[p][i] = ldn<F32>(nmean, base + (size_t)(s + PF3)*6144 + i*DDIM);
            }
            const int k = c*CL + s;
            const float* A = As + s*36;      // LDS
            float acc[6];
            #pragma unroll
            for (int i = 0; i < 6; ++i){
                float t = n[i];
                #pragma unroll
                for (int mm = 0; mm < 6; ++mm) t += A[i*6+mm]*m[mm];
                acc[i] = t;
            }
            #pragma unroll
            for (int i = 0; i < 6; ++i){
                m[i] = acc[i];
                if (F32){
                    ((float*)means_out)[(size_t)k*6144 + i*DDIM + col] = m[i];
                } else {
                    ((uint16_t*)means_out)[(size_t)k*6144 + i*DDIM + col] = f2bf(m[i]);
                }
            }
        }
    }
}

// ---------------------------------------------------------------------------
// L1 = km1 (waves 0-3) + k1 compose (wave 4 of every 4th block).
// 256 blocks x 320 threads. As/Ns staged once, shared by both roles.
// Compose is the round-8 shuffle recursion (zero barriers), bitwise-identical.
// ---------------------------------------------------------------------------
__global__ void __launch_bounds__(320)
L1_km1_compose(const void* __restrict__ imean, const void* __restrict__ trans,
               const void* __restrict__ ncov, const void* __restrict__ nmean,
               double* __restrict__ Pd, double* __restrict__ Qd,
               float* __restrict__ Pf, float* __restrict__ r_ws){
    __shared__ float As[CL*36], Ns[CL*36];
    __shared__ uint32_t s_flag;
    const int b = blockIdx.x;
    const int c = b >> 2;
    const int tid = threadIdx.x;
    if (tid < 64){
        uint32_t fl = detect_wave(imean);
        if (tid == 0) s_flag = fl;
    }
    __syncthreads();
    const bool f32 = s_flag != 0;
    for (int idx = tid; idx < CL*36; idx += 320){
        const size_t g = (size_t)c*CL*36 + idx;
        As[idx] = ld(trans, g, f32);
        Ns[idx] = ld(ncov,  g, f32);
    }
    __syncthreads();
    if (tid < 256){
        const int col = (b & 3)*256 + tid;
        if (f32) km1_body<true >(nmean, As, r_ws, c, col);
        else     km1_body<false>(nmean, As, r_ws, c, col);
    } else if ((b & 3) == 0){
        // wave 4: P/Q compose for chunk c (shuffle recursion, no barriers)
        const int e  = tid - 256;            // lane within wave 4
        const int ec = (e < 36) ? e : 0;
        const int i = ec / 6, j = ec % 6;
        const int i6 = i*6, j6 = j*6;
        double P = (i == j) ? 1.0 : 0.0, Q = 0.0;
        for (int s = 0; s < CL; ++s){
            const float* A  = As + s*36;
            const float* Nn = Ns + s*36;
            double newP = 0.0, Tij = 0.0;
            #pragma unroll
            for (int m = 0; m < 6; ++m){
                double am = (double)A[i6+m];
                newP += am * __shfl(P, m*6+j, 64);   // P[m][j]
                Tij  += am * __shfl(Q, m*6+j, 64);   // Q[m][j]
            }
            double qn = 0.0;
            #pragma unroll
            for (int m = 0; m < 6; ++m){
                qn += __shfl(Tij, i6+m, 64) * (double)A[j6+m];
                qn += (double)Nn[i6+m] * (double)Nn[j6+m];
            }
            P = newP; Q = qn;
        }
        if (e < 36){
            Pd[c*36+e] = P;
            Qd[c*36+e] = Q;
            Pf[c*36+e] = (float)P;
        }
    }
}

// ---------------------------------------------------------------------------
// L2 = km2 (blocks 0-3) + k2 boundary scan (block 4, wave 0).
// Bodies verbatim from round-8 km2_scan / k2_boundary_scan.
// ---------------------------------------------------------------------------
__global__ void __launch_bounds__(256)
L2_scans(const void* __restrict__ imean, const void* __restrict__ icov,
         const float* __restrict__ Pf,
         const double* __restrict__ Pd, const double* __restrict__ Qd,
         const float* __restrict__ r_ws,
         float* __restrict__ mb_ws, double* __restrict__ Mb){
    __shared__ float  Psf[CH*36];            // km2 stage (blocks 0-3)
    __shared__ double Psd[CH*36], Qsd[CH*36], l_ds[36];   // k2 stage (block 4)
    __shared__ uint32_t s_flag;
    const int b = blockIdx.x;
    const int tid = threadIdx.x;
    if (tid < 64){
        uint32_t fl = detect_wave(imean);
        if (tid == 0) s_flag = fl;
    }
    __syncthreads();
    const bool f32 = s_flag != 0;

    if (b < 4){
        for (int idx = tid; idx < CH*36; idx += 256) Psf[idx] = Pf[idx];
        __syncthreads();
        const int col = b*256 + tid;
        float m[6];
        #pragma unroll
        for (int i = 0; i < 6; ++i) m[i] = ld(imean, (size_t)i*DDIM + col, f32);
        float rb[4][6];
        #pragma unroll
        for (int p = 0; p < 4; ++p)
            #pragma unroll
            for (int i = 0; i < 6; ++i) rb[p][i] = r_ws[(size_t)p*6144 + i*DDIM + col];
        for (int c0 = 0; c0 < CH; c0 += 4){
            const bool pf = (c0 + 4 < CH);   // uniform
            #pragma unroll
            for (int p = 0; p < 4; ++p){
                const int c = c0 + p;
                float rc[6];
                #pragma unroll
                for (int i = 0; i < 6; ++i) rc[i] = rb[p][i];
                if (pf){
                    #pragma unroll
                    for (int i = 0; i < 6; ++i)
                        rb[p][i] = r_ws[(size_t)(c+4)*6144 + i*DDIM + col];
                }
                float* mb = mb_ws + (size_t)c*6144;
                #pragma unroll
                for (int i = 0; i < 6; ++i) mb[i*DDIM + col] = m[i];
                float nm[6];
                #pragma unroll
                for (int i = 0; i < 6; ++i){
                    float s0 = rc[i];
                    #pragma unroll
                    for (int mm = 0; mm < 6; ++mm) s0 += Psf[c*36 + i*6+mm]*m[mm];
                    nm[i] = s0;
                }
                #pragma unroll
                for (int i = 0; i < 6; ++i) m[i] = nm[i];
            }
        }
    } else {
        // block 4: k2 boundary scan (wave 0 shuffle recursion)
        for (int idx = tid; idx < CH*36; idx += 256){
            Psd[idx] = Pd[idx];
            Qsd[idx] = Qd[idx];
        }
        if (tid < 36) l_ds[tid] = (double)ld(icov, tid, f32);
        __syncthreads();
        if (tid < 64){
            const int e  = tid;
            const int ec = (e < 36) ? e : 0;
            const int i = ec / 6, j = ec % 6;
            const int i6 = i*6, j6 = j*6;
            double M = 0.0;
            #pragma unroll
            for (int mm = 0; mm < 6; ++mm) M += l_ds[i6+mm] * l_ds[j6+mm];
            if (e < 36) Mb[e] = M;
            for (int cc = 0; cc < CH - 1; ++cc){
                const double* Pc = Psd + cc*36;
                double t = 0.0;
                #pragma unroll
                for (int m = 0; m < 6; ++m) t += Pc[i6+m] * __shfl(M, m*6+j, 64);
                double mn = 0.0;
                #pragma unroll
                for (int m = 0; m < 6; ++m) mn += __shfl(t, i6+m, 64) * Pc[j6+m];
                mn += Qsd[cc*36 + ec];
                M = mn;
                if (e < 36) Mb[(cc+1)*36 + e] = mn;
            }
        }
    }
}

// ---------------------------------------------------------------------------
// L3 = km3 (blocks 0-255) + k34 expand+QR (blocks 256-319, threads 0-63).
// Bodies verbatim from round-8 km3_final / k34_expand_qr.
// ---------------------------------------------------------------------------
__global__ void __launch_bounds__(256)
L3_final(const void* __restrict__ imean, const void* __restrict__ icov,
         const void* __restrict__ trans, const void* __restrict__ ncov,
         const void* __restrict__ nmean,
         const double* __restrict__ Mb, const float* __restrict__ mb_ws,
         void* __restrict__ d_out,
         uint32_t* __restrict__ masks, uint32_t* __restrict__ chunkTot){
    __shared__ float As[CL*36], Ns[CL*36];
    __shared__ double Mst[CL*37];            // stride 37: avoid row aliasing
    __shared__ uint32_t s_flag;
    const int b = blockIdx.x;
    const int tid = threadIdx.x;
    if (tid < 64){
        uint32_t fl = detect_wave(imean);
        if (tid == 0) s_flag = fl;
    }
    __syncthreads();
    const bool f32 = s_flag != 0;

    if (b < 256){
        // ---- km3 ----
        const int c = b >> 2;
        for (int idx = tid; idx < CL*36; idx += 256)
            As[idx] = ld(trans, (size_t)c*CL*36 + idx, f32);
        __syncthreads();
        const int col = (b & 3)*256 + tid;
        if (f32) km3_body<true >(nmean, As, mb_ws, d_out, c, col);
        else     km3_body<false>(nmean, As, mb_ws, d_out, c, col);
        return;
    }

    // ---- k34: expand + QR for chunk c ----
    const int c = b - 256;
    for (int idx = tid; idx < CL*36; idx += 256){
        const size_t g = (size_t)c*CL*36 + idx;
        As[idx] = ld(trans, g, f32);
        Ns[idx] = ld(ncov,  g, f32);
    }
    __syncthreads();

    if (tid < 64){
        const int e  = tid;
        const int ec = (e < 36) ? e : 0;
        const int i = ec / 6, j = ec % 6;
        const int i6 = i*6, j6 = j*6;
        double M = Mb[c*36 + ec];
        for (int s = 0; ; ++s){
            if (e < 36) Mst[s*37 + e] = M;   // M entering step s
            if (s == CL - 1) break;          // uniform
            const float* A  = As + s*36;
            const float* Nn = Ns + s*36;
            double t = 0.0;
            #pragma unroll
            for (int m = 0; m < 6; ++m) t += (double)A[i6+m] * __shfl(M, m*6+j, 64);
            double mn = 0.0;
            #pragma unroll
            for (int m = 0; m < 6; ++m){
                mn += __shfl(t, i6+m, 64) * (double)A[j6+m];
                mn += (double)Nn[i6+m] * (double)Nn[j6+m];
            }
            M = mn;
        }
    }
    __syncthreads();

    if (tid >= 64) return;
    const int e = tid;
    const int k = c*CL + e;
    double X[12][6];
    if (k == 0){
        double l0[6][6], A0[6][6];
        #pragma unroll
        for (int a = 0; a < 36; ++a){
            l0[a/6][a%6] = (double)ld(icov, a, f32);
            A0[a/6][a%6] = (double)As[a];
        }
        #pragma unroll
        for (int i2 = 0; i2 < 6; ++i2)
            #pragma unroll
            for (int j2 = 0; j2 < 6; ++j2){
                double s = 0.0;
                #pragma unroll
                for (int m = 0; m < 6; ++m) s += A0[i2][m] * l0[m][j2];
                X[j2][i2] = s;               // top block = (A l)^T
            }
    } else {
        double Mx[6][6];
        #pragma unroll
        for (int a = 0; a < 36; ++a) Mx[a/6][a%6] = Mst[e*37 + a];
        // Cholesky in place
        #pragma unroll
        for (int j2 = 0; j2 < 6; ++j2){
            double d = Mx[j2][j2];
            #pragma unroll
            for (int m = 0; m < 6; ++m) if (m < j2) d -= Mx[j2][m]*Mx[j2][m];
            d = (d > 1e-300) ? d : 1e-300;
            double cjj = sqrt(d);
            Mx[j2][j2] = cjj;
            double inv = 1.0 / cjj;
            #pragma unroll
            for (int i2 = 0; i2 < 6; ++i2){
                if (i2 > j2){
                    double s = Mx[i2][j2];
                    #pragma unroll
                    for (int m = 0; m < 6; ++m) if (m < j2) s -= Mx[i2][m]*Mx[j2][m];
                    Mx[i2][j2] = s * inv;
                }
            }
        }
        #pragma unroll
        for (int i2 = 0; i2 < 6; ++i2){
            double Arow[6];
            #pragma unroll
            for (int m = 0; m < 6; ++m) Arow[m] = (double)As[e*36 + i2*6 + m];
            #pragma unroll
            for (int j2 = 0; j2 < 6; ++j2){
                double s = 0.0;
                #pragma unroll
                for (int m = 0; m < 6; ++m) if (m >= j2) s += Arow[m] * Mx[m][j2];
                X[j2][i2] = s;               // top block = (A C)^T
            }
        }
    }
    // bottom block = n^T
    #pragma unroll
    for (int r = 0; r < 6; ++r)
        #pragma unroll
        for (int c2 = 0; c2 < 6; ++c2)
            X[6+r][c2] = (double)Ns[e*36 + c2*6 + r];

    // In-place Householder QR, LAPACK sign convention
    #pragma unroll
    for (int kk = 0; kk < 6; ++kk){
        double alpha = X[kk][kk];
        double xn2 = 0.0;
        #pragma unroll
        for (int i2 = 0; i2 < 12; ++i2) if (i2 > kk) xn2 += X[i2][kk]*X[i2][kk];
        if (xn2 != 0.0){
            double nrm  = sqrt(alpha*alpha + xn2);
            double beta = (alpha >= 0.0) ? -nrm : nrm;
            double tau  = (beta - alpha) / beta;
            double sc   = 1.0 / (alpha - beta);
            #pragma unroll
            for (int i2 = 0; i2 < 12; ++i2) if (i2 > kk) X[i2][kk] *= sc;
            X[kk][kk] = beta;
            #pragma unroll
            for (int j2 = 0; j2 < 6; ++j2){
                if (j2 > kk){
                    double w = X[kk][j2];
                    #pragma unroll
                    for (int i2 = 0; i2 < 12; ++i2) if (i2 > kk) w += X[i2][kk]*X[i2][j2];
                    double wt = tau * w;
                    X[kk][j2] -= wt;
                    #pragma unroll
                    for (int i2 = 0; i2 < 12; ++i2) if (i2 > kk) X[i2][j2] -= X[i2][kk]*wt;
                }
            }
        }
    }

    uint32_t mask = 0;
    #pragma unroll
    for (int j2 = 0; j2 < 6; ++j2) if (X[j2][j2] < 0.0) mask |= (1u << j2);
    masks[k] = mask;

    // per-chunk XOR total for L4's cross-chunk prefix
    uint32_t incl = mask;
    #pragma unroll
    for (int ofs = 1; ofs < 64; ofs <<= 1){
        uint32_t up = (uint32_t)__shfl_up((int)incl, ofs, 64);
        if (e >= ofs) incl ^= up;
    }
    if (e == 63) chunkTot[c] = incl;

    if (f32){
        float* o = (float*)d_out + MEAN_ELEMS + (size_t)k*36;
        #pragma unroll
        for (int i2 = 0; i2 < 6; ++i2)
            #pragma unroll
            for (int j2 = 0; j2 < 6; ++j2)
                o[i2*6 + j2] = (j2 <= i2) ? (float)X[j2][i2] : 0.0f;
    } else {
        uint16_t* o = (uint16_t*)d_out + MEAN_ELEMS + (size_t)k*36;
        #pragma unroll
        for (int i2 = 0; i2 < 6; ++i2)
            #pragma unroll
            for (int j2 = 0; j2 < 6; ++j2)
                o[i2*6 + j2] = f2bf((j2 <= i2) ? (float)X[j2][i2] : 0.0f);
    }
}

// ---------------------------------------------------------------------------
// L4 = k56: cross-chunk sign prefix + apply (verbatim from round 8).
// ---------------------------------------------------------------------------
__global__ void __launch_bounds__(64)
L4_sign_apply(const void* __restrict__ imean,
              void* __restrict__ d_out,
              const uint32_t* __restrict__ masks,
              const uint32_t* __restrict__ chunkTot){
    __shared__ uint32_t s_flag;
    const int c = blockIdx.x;
    const int e = threadIdx.x;
    {
        uint32_t fl = detect_wave(imean);
        if (e == 0) s_flag = fl;
    }
    __syncthreads();
    const bool f32 = s_flag != 0;
    const int k = c*CL + e;
    const uint32_t m = masks[k];
    uint32_t incl = m;
    #pragma unroll
    for (int ofs = 1; ofs < 64; ofs <<= 1){
        uint32_t up = (uint32_t)__shfl_up((int)incl, ofs, 64);
        if (e >= ofs) incl ^= up;
    }
    const uint32_t excl = incl ^ m;
    uint32_t v = (e < c) ? chunkTot[e] : 0u;   // c<=63 -> lanes 0..62 suffice
    #pragma unroll
    for (int ofs = 32; ofs >= 1; ofs >>= 1) v ^= (uint32_t)__shfl_xor((int)v, ofs, 64);
    const uint32_t am = v ^ excl;              // == old amask[k]
    if (am == 0u) return;
    if (f32){
        uint32_t* o = (uint32_t*)d_out + MEAN_ELEMS + (size_t)k*36;
        #pragma unroll
        for (int t = 0; t < 36; ++t)
            if ((am >> (t % 6)) & 1u) o[t] ^= 0x80000000u;
    } else {
        uint16_t* o = (uint16_t*)d_out + MEAN_ELEMS + (size_t)k*36;
        #pragma unroll
        for (int t = 0; t < 36; ++t)
            if ((am >> (t % 6)) & 1u) o[t] ^= 0x8000u;
    }
}

// ---------------------------------------------------------------------------
extern "C" void kernel_launch(void* const* d_in, const int* in_sizes, int n_in,
                              void* d_out, int out_size, void* d_ws, size_t ws_size,
                              hipStream_t stream){
    (void)in_sizes; (void)n_in; (void)out_size; (void)ws_size;
    const void* imean = d_in[0];  // [6,1024]
    const void* icov  = d_in[1];  // [6,6]
    const void* trans = d_in[2];  // [T,6,6]
    const void* nmean = d_in[3];  // [T,6,1024]
    const void* ncov  = d_in[4];  // [T,6,6]

    // workspace layout (8-byte types first; ~3.2 MB total)
    char* w = (char*)d_ws;
    double* Pd   = (double*)w; w += (size_t)CH*36*8;
    double* Qd   = (double*)w; w += (size_t)CH*36*8;
    double* Mb   = (double*)w; w += (size_t)CH*36*8;
    float*  Pf   = (float*)w;  w += (size_t)CH*36*4;
    uint32_t* masks    = (uint32_t*)w; w += (size_t)T_STEPS*4;
    uint32_t* chunkTot = (uint32_t*)w; w += (size_t)CH*4;
    float* r_ws  = (float*)w;  w += (size_t)CH*6*DDIM*4;
    float* mb_ws = (float*)w;  w += (size_t)CH*6*DDIM*4;

    L1_km1_compose<<<4*CH, 320, 0, stream>>>(imean, trans, ncov, nmean,
                                             Pd, Qd, Pf, r_ws);
    L2_scans<<<5, 256, 0, stream>>>(imean, icov, Pf, Pd, Qd, r_ws, mb_ws, Mb);
    L3_final<<<4*CH + CH, 256, 0, stream>>>(imean, icov, trans, ncov, nmean,
                                            Mb, mb_ws, d_out, masks, chunkTot);
    L4_sign_apply<<<CH, 64, 0, stream>>>(imean, d_out, masks, chunkTot);
}

// Round 10
// 304.389 us; speedup vs baseline: 1.2517x; 1.2034x over previous
//
#include <hip/hip_runtime.h>
#include <stdint.h>

// Problem constants (n=6, d=1024, T=4096)
#define T_STEPS 4096
#define DDIM    1024
#define CH      64    // chunks (both pipelines)
#define CL      64    // steps per chunk
#define MEAN_ELEMS ((size_t)T_STEPS * 6 * DDIM)   // 25,165,824

#define PF1 8   // km1 nmean prefetch depth (8*6=48 outstanding <= 63 vmcnt cap)
#define PF3 4   // km3 depth (loads+stores: 3*12+6=42 <= 63)

__device__ __forceinline__ float bf2f(uint16_t h){
    return __uint_as_float(((uint32_t)h) << 16);
}
__device__ __forceinline__ uint16_t f2bf(float f){   // round-to-nearest-even
    uint32_t u = __float_as_uint(f);
    uint32_t r = 0x7FFFu + ((u >> 16) & 1u);
    return (uint16_t)((u + r) >> 16);
}
// dtype-flag-aware scalar load (flag: 1 = inputs are float32, 0 = bf16)
__device__ __forceinline__ float ld(const void* p, size_t idx, bool f32){
    return f32 ? ((const float*)p)[idx] : bf2f(((const uint16_t*)p)[idx]);
}
template<bool F32>
__device__ __forceinline__ float ldn(const void* p, size_t idx){
    return F32 ? ((const float*)p)[idx] : bf2f(((const uint16_t*)p)[idx]);
}

// Per-wave dtype detect (one wave; same data every block -> deterministic).
__device__ __forceinline__ uint32_t detect_wave(const void* imean){
    const uint32_t* w = (const uint32_t*)imean;
    int good = 0;
    for (int i = (int)(threadIdx.x & 63); i < 3072; i += 64){
        float v = bf2f((uint16_t)(w[i] & 0xFFFFu));
        float a = fabsf(v);
        if (a > 1e-6f && a < 1e4f) good++;
    }
    #pragma unroll
    for (int ofs = 32; ofs >= 1; ofs >>= 1) good += __shfl_xor(good, ofs, 64);
    return (good < 2000) ? 1u : 0u;
}

// ---------------------------------------------------------------------------
// K1: per-chunk P/Q compose, single wave, shuffle recursion (round-8 version,
// ~6 us). Kept SEPARATE from km1: merging it forced launch_bounds(320) ->
// VGPR cap 128 -> km1's pb[8][6] spilled to scratch (213 MB writes, 159 us).
// ---------------------------------------------------------------------------
__global__ void __launch_bounds__(64)
k1_chunk_compose(const void* __restrict__ imean,
                 const void* __restrict__ trans,
                 const void* __restrict__ ncov,
                 double* __restrict__ Pd, double* __restrict__ Qd,
                 float* __restrict__ Pf){
    __shared__ float As[CL*36], Ns[CL*36];
    __shared__ uint32_t s_flag;
    const int c = blockIdx.x;
    const int e = threadIdx.x;
    const int ec = (e < 36) ? e : 0;       // lanes 36-63 mirror lane 0 (discarded)
    const int i = ec / 6, j = ec % 6;
    const int i6 = i*6, j6 = j*6;
    {
        uint32_t fl = detect_wave(imean);
        if (e == 0) s_flag = fl;
    }
    __syncthreads();
    const bool f32 = s_flag != 0;
    for (int idx = e; idx < CL*36; idx += 64){
        const size_t g = (size_t)c*CL*36 + idx;
        As[idx] = ld(trans, g, f32);
        Ns[idx] = ld(ncov,  g, f32);
    }
    __syncthreads();
    double P = (i == j) ? 1.0 : 0.0, Q = 0.0;
    for (int s = 0; s < CL; ++s){
        const float* A  = As + s*36;
        const float* Nn = Ns + s*36;
        double newP = 0.0, Tij = 0.0;
        #pragma unroll
        for (int m = 0; m < 6; ++m){
            double am = (double)A[i6+m];
            newP += am * __shfl(P, m*6+j, 64);   // P[m][j]
            Tij  += am * __shfl(Q, m*6+j, 64);   // Q[m][j]
        }
        double qn = 0.0;
        #pragma unroll
        for (int m = 0; m < 6; ++m){
            qn += __shfl(Tij, i6+m, 64) * (double)A[j6+m];     // T[i][m]*A[j][m]
            qn += (double)Nn[i6+m] * (double)Nn[j6+m];         // + n n^T
        }
        P = newP; Q = qn;
    }
    if (e < 36){
        Pd[c*36+e] = P;
        Qd[c*36+e] = Q;
        Pf[c*36+e] = (float)P;
    }
}

// ---------------------------------------------------------------------------
// Means bodies (verbatim from passing round-8 kernel).
// ---------------------------------------------------------------------------
template<bool F32>
__device__ __forceinline__ void km1_body(const void* __restrict__ nmean,
                                         const float* __restrict__ As,
                                         float* __restrict__ r_ws, int c, int col){
    float r[6];
    #pragma unroll
    for (int i = 0; i < 6; ++i) r[i] = 0.f;
    float pb[PF1][6];
    const size_t base = (size_t)c*CL*6144 + col;
    #pragma unroll
    for (int p = 0; p < PF1; ++p)
        #pragma unroll
        for (int i = 0; i < 6; ++i)
            pb[p][i] = ldn<F32>(nmean, base + (size_t)p*6144 + i*DDIM);
    for (int s0 = 0; s0 < CL; s0 += PF1){
        const bool pf = (s0 + PF1 < CL);     // uniform
        #pragma unroll
        for (int p = 0; p < PF1; ++p){
            const int s = s0 + p;
            float n[6];
            #pragma unroll
            for (int i = 0; i < 6; ++i) n[i] = pb[p][i];
            if (pf){
                #pragma unroll
                for (int i = 0; i < 6; ++i)
                    pb[p][i] = ldn<F32>(nmean, base + (size_t)(s + PF1)*6144 + i*DDIM);
            }
            const float* A = As + s*36;      // LDS (lgkmcnt, not vmcnt)
            float acc[6];
            #pragma unroll
            for (int i = 0; i < 6; ++i){
                float t = n[i];
                #pragma unroll
                for (int m = 0; m < 6; ++m) t += A[i*6+m]*r[m];
                acc[i] = t;
            }
            #pragma unroll
            for (int i = 0; i < 6; ++i) r[i] = acc[i];
        }
    }
    float* out = r_ws + (size_t)c*6144;
    #pragma unroll
    for (int i = 0; i < 6; ++i) out[i*DDIM + col] = r[i];
}

__global__ void __launch_bounds__(256)
km1_chunk_r(const void* __restrict__ imean, const void* __restrict__ trans,
            const void* __restrict__ nmean,
            float* __restrict__ r_ws){
    __shared__ float As[CL*36];
    __shared__ uint32_t s_flag;
    if (threadIdx.x < 64){
        uint32_t fl = detect_wave(imean);
        if (threadIdx.x == 0) s_flag = fl;
    }
    __syncthreads();
    const bool f32 = s_flag != 0;
    const int c = blockIdx.x >> 2;
    for (int idx = threadIdx.x; idx < CL*36; idx += 256)
        As[idx] = ld(trans, (size_t)c*CL*36 + idx, f32);
    __syncthreads();
    const int col = (blockIdx.x & 3)*256 + threadIdx.x;
    if (f32) km1_body<true >(nmean, As, r_ws, c, col);
    else     km1_body<false>(nmean, As, r_ws, c, col);
}

template<bool F32>
__device__ __forceinline__ void km3_body(const void* __restrict__ nmean,
                                         const float* __restrict__ As,
                                         const float* __restrict__ mb_ws,
                                         void* __restrict__ means_out,
                                         int c, int col){
    float m[6];
    const float* mb = mb_ws + (size_t)c*6144;
    #pragma unroll
    for (int i = 0; i < 6; ++i) m[i] = mb[i*DDIM + col];
    float pb[PF3][6];
    const size_t base = (size_t)c*CL*6144 + col;
    #pragma unroll
    for (int p = 0; p < PF3; ++p)
        #pragma unroll
        for (int i = 0; i < 6; ++i)
            pb[p][i] = ldn<F32>(nmean, base + (size_t)p*6144 + i*DDIM);
    for (int s0 = 0; s0 < CL; s0 += PF3){
        const bool pf = (s0 + PF3 < CL);     // uniform
        #pragma unroll
        for (int p = 0; p < PF3; ++p){
            const int s = s0 + p;
            float n[6];
            #pragma unroll
            for (int i = 0; i < 6; ++i) n[i] = pb[p][i];
            if (pf){
                #pragma unroll
                for (int i = 0; i < 6; ++i)
                    pb[p][i] = ldn<F32>(nmean, base + (size_t)(s + PF3)*6144 + i*DDIM);
            }
            const int k = c*CL + s;
            const float* A = As + s*36;      // LDS
            float acc[6];
            #pragma unroll
            for (int i = 0; i < 6; ++i){
                float t = n[i];
                #pragma unroll
                for (int mm = 0; mm < 6; ++mm) t += A[i*6+mm]*m[mm];
                acc[i] = t;
            }
            #pragma unroll
            for (int i = 0; i < 6; ++i){
                m[i] = acc[i];
                if (F32){
                    ((float*)means_out)[(size_t)k*6144 + i*DDIM + col] = m[i];
                } else {
                    ((uint16_t*)means_out)[(size_t)k*6144 + i*DDIM + col] = f2bf(m[i]);
                }
            }
        }
    }
}

// ---------------------------------------------------------------------------
// L2 = km2 (blocks 0-3) + k2 boundary scan (block 4, wave 0).
// ---------------------------------------------------------------------------
__global__ void __launch_bounds__(256)
L2_scans(const void* __restrict__ imean, const void* __restrict__ icov,
         const float* __restrict__ Pf,
         const double* __restrict__ Pd, const double* __restrict__ Qd,
         const float* __restrict__ r_ws,
         float* __restrict__ mb_ws, double* __restrict__ Mb){
    __shared__ float  Psf[CH*36];            // km2 stage (blocks 0-3)
    __shared__ double Psd[CH*36], Qsd[CH*36], l_ds[36];   // k2 stage (block 4)
    __shared__ uint32_t s_flag;
    const int b = blockIdx.x;
    const int tid = threadIdx.x;
    if (tid < 64){
        uint32_t fl = detect_wave(imean);
        if (tid == 0) s_flag = fl;
    }
    __syncthreads();
    const bool f32 = s_flag != 0;

    if (b < 4){
        for (int idx = tid; idx < CH*36; idx += 256) Psf[idx] = Pf[idx];
        __syncthreads();
        const int col = b*256 + tid;
        float m[6];
        #pragma unroll
        for (int i = 0; i < 6; ++i) m[i] = ld(imean, (size_t)i*DDIM + col, f32);
        float rb[4][6];
        #pragma unroll
        for (int p = 0; p < 4; ++p)
            #pragma unroll
            for (int i = 0; i < 6; ++i) rb[p][i] = r_ws[(size_t)p*6144 + i*DDIM + col];
        for (int c0 = 0; c0 < CH; c0 += 4){
            const bool pf = (c0 + 4 < CH);   // uniform
            #pragma unroll
            for (int p = 0; p < 4; ++p){
                const int c = c0 + p;
                float rc[6];
                #pragma unroll
                for (int i = 0; i < 6; ++i) rc[i] = rb[p][i];
                if (pf){
                    #pragma unroll
                    for (int i = 0; i < 6; ++i)
                        rb[p][i] = r_ws[(size_t)(c+4)*6144 + i*DDIM + col];
                }
                float* mb = mb_ws + (size_t)c*6144;
                #pragma unroll
                for (int i = 0; i < 6; ++i) mb[i*DDIM + col] = m[i];
                float nm[6];
                #pragma unroll
                for (int i = 0; i < 6; ++i){
                    float s0 = rc[i];
                    #pragma unroll
                    for (int mm = 0; mm < 6; ++mm) s0 += Psf[c*36 + i*6+mm]*m[mm];
                    nm[i] = s0;
                }
                #pragma unroll
                for (int i = 0; i < 6; ++i) m[i] = nm[i];
            }
        }
    } else {
        // block 4: k2 boundary scan (wave 0 shuffle recursion)
        for (int idx = tid; idx < CH*36; idx += 256){
            Psd[idx] = Pd[idx];
            Qsd[idx] = Qd[idx];
        }
        if (tid < 36) l_ds[tid] = (double)ld(icov, tid, f32);
        __syncthreads();
        if (tid < 64){
            const int e  = tid;
            const int ec = (e < 36) ? e : 0;
            const int i = ec / 6, j = ec % 6;
            const int i6 = i*6, j6 = j*6;
            double M = 0.0;
            #pragma unroll
            for (int mm = 0; mm < 6; ++mm) M += l_ds[i6+mm] * l_ds[j6+mm];
            if (e < 36) Mb[e] = M;
            for (int cc = 0; cc < CH - 1; ++cc){
                const double* Pc = Psd + cc*36;
                double t = 0.0;
                #pragma unroll
                for (int m = 0; m < 6; ++m) t += Pc[i6+m] * __shfl(M, m*6+j, 64);
                double mn = 0.0;
                #pragma unroll
                for (int m = 0; m < 6; ++m) mn += __shfl(t, i6+m, 64) * Pc[j6+m];
                mn += Qsd[cc*36 + ec];
                M = mn;
                if (e < 36) Mb[(cc+1)*36 + e] = mn;
            }
        }
    }
}

// ---------------------------------------------------------------------------
// L3 = km3 (blocks 0-255) + k34 expand+QR (blocks 256-319, threads 0-63).
// ---------------------------------------------------------------------------
__global__ void __launch_bounds__(256)
L3_final(const void* __restrict__ imean, const void* __restrict__ icov,
         const void* __restrict__ trans, const void* __restrict__ ncov,
         const void* __restrict__ nmean,
         const double* __restrict__ Mb, const float* __restrict__ mb_ws,
         void* __restrict__ d_out,
         uint32_t* __restrict__ masks, uint32_t* __restrict__ chunkTot){
    __shared__ float As[CL*36], Ns[CL*36];
    __shared__ double Mst[CL*37];            // stride 37: avoid row aliasing
    __shared__ uint32_t s_flag;
    const int b = blockIdx.x;
    const int tid = threadIdx.x;
    if (tid < 64){
        uint32_t fl = detect_wave(imean);
        if (tid == 0) s_flag = fl;
    }
    __syncthreads();
    const bool f32 = s_flag != 0;

    if (b < 256){
        // ---- km3 ----
        const int c = b >> 2;
        for (int idx = tid; idx < CL*36; idx += 256)
            As[idx] = ld(trans, (size_t)c*CL*36 + idx, f32);
        __syncthreads();
        const int col = (b & 3)*256 + tid;
        if (f32) km3_body<true >(nmean, As, mb_ws, d_out, c, col);
        else     km3_body<false>(nmean, As, mb_ws, d_out, c, col);
        return;
    }

    // ---- k34: expand + QR for chunk c ----
    const int c = b - 256;
    for (int idx = tid; idx < CL*36; idx += 256){
        const size_t g = (size_t)c*CL*36 + idx;
        As[idx] = ld(trans, g, f32);
        Ns[idx] = ld(ncov,  g, f32);
    }
    __syncthreads();

    if (tid < 64){
        const int e  = tid;
        const int ec = (e < 36) ? e : 0;
        const int i = ec / 6, j = ec % 6;
        const int i6 = i*6, j6 = j*6;
        double M = Mb[c*36 + ec];
        for (int s = 0; ; ++s){
            if (e < 36) Mst[s*37 + e] = M;   // M entering step s
            if (s == CL - 1) break;          // uniform
            const float* A  = As + s*36;
            const float* Nn = Ns + s*36;
            double t = 0.0;
            #pragma unroll
            for (int m = 0; m < 6; ++m) t += (double)A[i6+m] * __shfl(M, m*6+j, 64);
            double mn = 0.0;
            #pragma unroll
            for (int m = 0; m < 6; ++m){
                mn += __shfl(t, i6+m, 64) * (double)A[j6+m];
                mn += (double)Nn[i6+m] * (double)Nn[j6+m];
            }
            M = mn;
        }
    }
    __syncthreads();

    if (tid >= 64) return;
    const int e = tid;
    const int k = c*CL + e;
    double X[12][6];
    if (k == 0){
        double l0[6][6], A0[6][6];
        #pragma unroll
        for (int a = 0; a < 36; ++a){
            l0[a/6][a%6] = (double)ld(icov, a, f32);
            A0[a/6][a%6] = (double)As[a];
        }
        #pragma unroll
        for (int i2 = 0; i2 < 6; ++i2)
            #pragma unroll
            for (int j2 = 0; j2 < 6; ++j2){
                double s = 0.0;
                #pragma unroll
                for (int m = 0; m < 6; ++m) s += A0[i2][m] * l0[m][j2];
                X[j2][i2] = s;               // top block = (A l)^T
            }
    } else {
        double Mx[6][6];
        #pragma unroll
        for (int a = 0; a < 36; ++a) Mx[a/6][a%6] = Mst[e*37 + a];
        // Cholesky in place
        #pragma unroll
        for (int j2 = 0; j2 < 6; ++j2){
            double d = Mx[j2][j2];
            #pragma unroll
            for (int m = 0; m < 6; ++m) if (m < j2) d -= Mx[j2][m]*Mx[j2][m];
            d = (d > 1e-300) ? d : 1e-300;
            double cjj = sqrt(d);
            Mx[j2][j2] = cjj;
            double inv = 1.0 / cjj;
            #pragma unroll
            for (int i2 = 0; i2 < 6; ++i2){
                if (i2 > j2){
                    double s = Mx[i2][j2];
                    #pragma unroll
                    for (int m = 0; m < 6; ++m) if (m < j2) s -= Mx[i2][m]*Mx[j2][m];
                    Mx[i2][j2] = s * inv;
                }
            }
        }
        #pragma unroll
        for (int i2 = 0; i2 < 6; ++i2){
            double Arow[6];
            #pragma unroll
            for (int m = 0; m < 6; ++m) Arow[m] = (double)As[e*36 + i2*6 + m];
            #pragma unroll
            for (int j2 = 0; j2 < 6; ++j2){
                double s = 0.0;
                #pragma unroll
                for (int m = 0; m < 6; ++m) if (m >= j2) s += Arow[m] * Mx[m][j2];
                X[j2][i2] = s;               // top block = (A C)^T
            }
        }
    }
    // bottom block = n^T
    #pragma unroll
    for (int r = 0; r < 6; ++r)
        #pragma unroll
        for (int c2 = 0; c2 < 6; ++c2)
            X[6+r][c2] = (double)Ns[e*36 + c2*6 + r];

    // In-place Householder QR, LAPACK sign convention
    #pragma unroll
    for (int kk = 0; kk < 6; ++kk){
        double alpha = X[kk][kk];
        double xn2 = 0.0;
        #pragma unroll
        for (int i2 = 0; i2 < 12; ++i2) if (i2 > kk) xn2 += X[i2][kk]*X[i2][kk];
        if (xn2 != 0.0){
            double nrm  = sqrt(alpha*alpha + xn2);
            double beta = (alpha >= 0.0) ? -nrm : nrm;
            double tau  = (beta - alpha) / beta;
            double sc   = 1.0 / (alpha - beta);
            #pragma unroll
            for (int i2 = 0; i2 < 12; ++i2) if (i2 > kk) X[i2][kk] *= sc;
            X[kk][kk] = beta;
            #pragma unroll
            for (int j2 = 0; j2 < 6; ++j2){
                if (j2 > kk){
                    double w = X[kk][j2];
                    #pragma unroll
                    for (int i2 = 0; i2 < 12; ++i2) if (i2 > kk) w += X[i2][kk]*X[i2][j2];
                    double wt = tau * w;
                    X[kk][j2] -= wt;
                    #pragma unroll
                    for (int i2 = 0; i2 < 12; ++i2) if (i2 > kk) X[i2][j2] -= X[i2][kk]*wt;
                }
            }
        }
    }

    uint32_t mask = 0;
    #pragma unroll
    for (int j2 = 0; j2 < 6; ++j2) if (X[j2][j2] < 0.0) mask |= (1u << j2);
    masks[k] = mask;

    // per-chunk XOR total for L4's cross-chunk prefix
    uint32_t incl = mask;
    #pragma unroll
    for (int ofs = 1; ofs < 64; ofs <<= 1){
        uint32_t up = (uint32_t)__shfl_up((int)incl, ofs, 64);
        if (e >= ofs) incl ^= up;
    }
    if (e == 63) chunkTot[c] = incl;

    if (f32){
        float* o = (float*)d_out + MEAN_ELEMS + (size_t)k*36;
        #pragma unroll
        for (int i2 = 0; i2 < 6; ++i2)
            #pragma unroll
            for (int j2 = 0; j2 < 6; ++j2)
                o[i2*6 + j2] = (j2 <= i2) ? (float)X[j2][i2] : 0.0f;
    } else {
        uint16_t* o = (uint16_t*)d_out + MEAN_ELEMS + (size_t)k*36;
        #pragma unroll
        for (int i2 = 0; i2 < 6; ++i2)
            #pragma unroll
            for (int j2 = 0; j2 < 6; ++j2)
                o[i2*6 + j2] = f2bf((j2 <= i2) ? (float)X[j2][i2] : 0.0f);
    }
}

// ---------------------------------------------------------------------------
// L4 = k56: cross-chunk sign prefix + apply.
// ---------------------------------------------------------------------------
__global__ void __launch_bounds__(64)
L4_sign_apply(const void* __restrict__ imean,
              void* __restrict__ d_out,
              const uint32_t* __restrict__ masks,
              const uint32_t* __restrict__ chunkTot){
    __shared__ uint32_t s_flag;
    const int c = blockIdx.x;
    const int e = threadIdx.x;
    {
        uint32_t fl = detect_wave(imean);
        if (e == 0) s_flag = fl;
    }
    __syncthreads();
    const bool f32 = s_flag != 0;
    const int k = c*CL + e;
    const uint32_t m = masks[k];
    uint32_t incl = m;
    #pragma unroll
    for (int ofs = 1; ofs < 64; ofs <<= 1){
        uint32_t up = (uint32_t)__shfl_up((int)incl, ofs, 64);
        if (e >= ofs) incl ^= up;
    }
    const uint32_t excl = incl ^ m;
    uint32_t v = (e < c) ? chunkTot[e] : 0u;   // c<=63 -> lanes 0..62 suffice
    #pragma unroll
    for (int ofs = 32; ofs >= 1; ofs >>= 1) v ^= (uint32_t)__shfl_xor((int)v, ofs, 64);
    const uint32_t am = v ^ excl;              // == old amask[k]
    if (am == 0u) return;
    if (f32){
        uint32_t* o = (uint32_t*)d_out + MEAN_ELEMS + (size_t)k*36;
        #pragma unroll
        for (int t = 0; t < 36; ++t)
            if ((am >> (t % 6)) & 1u) o[t] ^= 0x80000000u;
    } else {
        uint16_t* o = (uint16_t*)d_out + MEAN_ELEMS + (size_t)k*36;
        #pragma unroll
        for (int t = 0; t < 36; ++t)
            if ((am >> (t % 6)) & 1u) o[t] ^= 0x8000u;
    }
}

// ---------------------------------------------------------------------------
extern "C" void kernel_launch(void* const* d_in, const int* in_sizes, int n_in,
                              void* d_out, int out_size, void* d_ws, size_t ws_size,
                              hipStream_t stream){
    (void)in_sizes; (void)n_in; (void)out_size; (void)ws_size;
    const void* imean = d_in[0];  // [6,1024]
    const void* icov  = d_in[1];  // [6,6]
    const void* trans = d_in[2];  // [T,6,6]
    const void* nmean = d_in[3];  // [T,6,1024]
    const void* ncov  = d_in[4];  // [T,6,6]

    // workspace layout (8-byte types first; ~3.2 MB total)
    char* w = (char*)d_ws;
    double* Pd   = (double*)w; w += (size_t)CH*36*8;
    double* Qd   = (double*)w; w += (size_t)CH*36*8;
    double* Mb   = (double*)w; w += (size_t)CH*36*8;
    float*  Pf   = (float*)w;  w += (size_t)CH*36*4;
    uint32_t* masks    = (uint32_t*)w; w += (size_t)T_STEPS*4;
    uint32_t* chunkTot = (uint32_t*)w; w += (size_t)CH*4;
    float* r_ws  = (float*)w;  w += (size_t)CH*6*DDIM*4;
    float* mb_ws = (float*)w;  w += (size_t)CH*6*DDIM*4;

    km1_chunk_r<<<4*CH, 256, 0, stream>>>(imean, trans, nmean, r_ws);
    k1_chunk_compose<<<CH, 64, 0, stream>>>(imean, trans, ncov, Pd, Qd, Pf);
    L2_scans<<<5, 256, 0, stream>>>(imean, icov, Pf, Pd, Qd, r_ws, mb_ws, Mb);
    L3_final<<<4*CH + CH, 256, 0, stream>>>(imean, icov, trans, ncov, nmean,
                                            Mb, mb_ws, d_out, masks, chunkTot);
    L4_sign_apply<<<CH, 64, 0, stream>>>(imean, d_out, masks, chunkTot);
}